// Round 9
// baseline (333.035 us; speedup 1.0000x reference)
//
#include <hip/hip_runtime.h>
#include <hip/hip_bf16.h>

typedef unsigned short ushort_t;
typedef __attribute__((ext_vector_type(8))) short bf16x8;
typedef __attribute__((ext_vector_type(4))) float f32x4;

#define B_SZ 4096
#define N_SZ 8
#define D_SZ 256
#define FF_SZ 2048
#define M_SZ (B_SZ * N_SZ)   // 32768
#define WELEM (D_SZ * D_SZ * N_SZ)  // 524288

__device__ inline float b2f(ushort_t u) {
    union { unsigned int i; float f; } t; t.i = ((unsigned int)u) << 16; return t.f;
}
__device__ inline ushort_t f2b(float f) {
    union { unsigned int i; float f; } t; t.f = f;
    unsigned int i = t.i;
    unsigned int r = (i + 0x7fffu + ((i >> 16) & 1u)) >> 16;
    return (ushort_t)r;
}

// async global->LDS, 16B per lane; LDS dest must be wave-uniform base + lane*16
__device__ inline void gl2lds16(const ushort_t* g, ushort_t* l) {
    __builtin_amdgcn_global_load_lds((const __attribute__((address_space(1))) void*)g,
                                     (__attribute__((address_space(3))) void*)l, 16, 0, 0);
}

// ---------------- convert/repack all weights f32 -> bf16 (unchanged, proven)
__global__ __launch_bounds__(256) void convert_weights(const float* __restrict__ w_in,
                                                       const float* __restrict__ w_out,
                                                       const float* __restrict__ W1,
                                                       const float* __restrict__ W2,
                                                       ushort_t* __restrict__ bt_in,
                                                       ushort_t* __restrict__ bt_out,
                                                       ushort_t* __restrict__ W1b,
                                                       ushort_t* __restrict__ W2b) {
    __shared__ float tile[64][65];
    const int bid = blockIdx.x;
    const int t = threadIdx.x;
    if (bid < 256) {
        const float* w = (bid < 128) ? w_in : w_out;
        ushort_t* bt = (bid < 128) ? bt_in : bt_out;
        const int id = bid & 127;
        const int d10 = (id >> 5) * 64;
        const int j0  = (id & 31) * 64;
#pragma unroll
        for (int it = 0; it < 16; ++it) {
            const int d1l = it * 4 + (t >> 6);
            const int jl = t & 63;
            tile[d1l][jl] = w[(size_t)(d10 + d1l) * 2048 + j0 + jl];
        }
        __syncthreads();
#pragma unroll
        for (int it = 0; it < 16; ++it) {
            const int jl = it * 4 + (t >> 6);
            const int d1l = t & 63;
            const int j = j0 + jl;
            bt[(size_t)(j >> 3) * 2048 + (j & 7) * 256 + d10 + d1l] = f2b(tile[d1l][jl]);
        }
    } else {
        const int id = bid - 256;
        const float* w = (id < 256) ? W1 : W2;
        ushort_t* o = (id < 256) ? W1b : W2b;
        const size_t base = (size_t)(id & 255) * 2048 + t * 8;
        const float4 a = *(const float4*)&w[base];
        const float4 b = *(const float4*)&w[base + 4];
        *(ushort4*)&o[base]     = make_ushort4(f2b(a.x), f2b(a.y), f2b(a.z), f2b(a.w));
        *(ushort4*)&o[base + 4] = make_ushort4(f2b(b.x), f2b(b.y), f2b(b.z), f2b(b.w));
    }
}

// ---------------- LN1: one WAVE per row of 256 (unchanged, proven)
__global__ __launch_bounds__(256) void ln_fast(const float* __restrict__ xin,
                                               const float* __restrict__ gam,
                                               const float* __restrict__ bet,
                                               ushort_t* __restrict__ out) {
    const int wave = threadIdx.x >> 6;
    const int lane = threadIdx.x & 63;
    const size_t row = (size_t)blockIdx.x * 4 + wave;
    const float4 v = *(const float4*)&xin[row * 256 + lane * 4];
    float s = v.x + v.y + v.z + v.w;
    float q = v.x * v.x + v.y * v.y + v.z * v.z + v.w * v.w;
#pragma unroll
    for (int off = 1; off < 64; off <<= 1) {
        s += __shfl_xor(s, off, 64);
        q += __shfl_xor(q, off, 64);
    }
    const float mu = s * (1.0f / 256.0f);
    const float var = q * (1.0f / 256.0f) - mu * mu;
    const float rs = rsqrtf(var + 1e-5f);
    const float4 g = *(const float4*)&gam[lane * 4];
    const float4 b = *(const float4*)&bet[lane * 4];
    ushort4 o;
    o.x = f2b((v.x - mu) * rs * g.x + b.x);
    o.y = f2b((v.y - mu) * rs * g.y + b.y);
    o.z = f2b((v.z - mu) * rs * g.z + b.z);
    o.w = f2b((v.w - mu) * rs * g.w + b.w);
    *(ushort4*)&out[row * 256 + lane * 4] = o;
}

// ============================================================================
// R18: R15 structure with A-OPERAND IN REGISTERS (global->VGPR, no LDS).
// R17 post-mortem arithmetic: per barrier-unit per CU the LDS pipe carries
// ~131 KB fragment reads + ~80 KB DMA writes ~= 1660 of ~1815 cycles (92%
// busy) -> MfmaUtil is LDS-capped at ~29% in ANY schedule. A-fragments are
// read with natural k-offsets, so they can come straight from global (L2-hot,
// 16B/lane; compiler inserts the vmcnt waits; read-only => no barrier/race
// interaction). This halves LDS fragment reads and removes A stage writes:
// ~1.6x on the bottleneck pipe. Bs staging/swizzle/barriers stay R15-proven.
// Freed As LDS: tt drops to ~34 KB -> 4 blocks/CU.
// ============================================================================

// ---------------- TT gemm + fused LN2 (grid 512, 4 blocks/CU)
__global__ __launch_bounds__(256, 4) void tt_ln2(const ushort_t* __restrict__ A,
                                                 const ushort_t* __restrict__ Bt0,
                                                 const ushort_t* __restrict__ Bt1,
                                                 const float* __restrict__ g2,
                                                 const float* __restrict__ be2,
                                                 const float* __restrict__ entf,
                                                 ushort_t* __restrict__ yn,
                                                 ushort_t* __restrict__ xb) {
    __shared__ __attribute__((aligned(16))) ushort_t Bs[256 * 64];   // 32 KB
    __shared__ float red_s[64 * 4];
    __shared__ float red_q[64 * 4];

    const int t = threadIdx.x;
    const int lb = ((blockIdx.x & 1) << 8) | (blockIdx.x >> 1);
    const int m0 = lb * 64;
    const int lane = t & 63;
    const int wc = t >> 6;
    const int l16 = lane & 15, quad = lane >> 4;
    const int tr = t >> 3;
    const int csw = (((t & 7) ^ (tr & 7)) << 3);

    const ushort_t* Bt = (m0 >= M_SZ / 2) ? Bt1 : Bt0;

    f32x4 acc[4][4];
#pragma unroll
    for (int i = 0; i < 4; i++)
#pragma unroll
        for (int j = 0; j < 4; j++) acc[i][j] = (f32x4)(0.0f);

#pragma unroll 1
    for (int kt = 0; kt < 32; ++kt) {
        const int kg = kt * 64;
        __syncthreads();   // previous unit's Bs reads complete before overwrite
#pragma unroll
        for (int p = 0; p < 8; ++p) {
            gl2lds16(Bt + (size_t)(p * 32 + tr) * 2048 + kg + csw, Bs + p * 2048 + t * 8);
        }
        __syncthreads();   // stage complete & visible

        const int s8 = kg >> 8;          // circulant shift, uniform in unit
#pragma unroll
        for (int kk = 0; kk < 2; ++kk) {
            const int ank = (((kk << 2) | quad) << 3);            // natural k-offset (A from global)
            const int ac  = ((((kk << 2) | quad) ^ (l16 & 7)) << 3);  // swizzled (Bs)
            const int kc  = (kg & 255) + ank;
            bf16x8 af[4], bfv[4];
#pragma unroll
            for (int i = 0; i < 4; i++) {
                const int rl = m0 + i * 16 + l16;
                const int srow = (rl & ~7) + (((rl & 7) - s8) & 7);
                af[i] = *(const bf16x8*)&A[(size_t)srow * 256 + kc];
            }
#pragma unroll
            for (int j = 0; j < 4; j++) bfv[j] = *(const bf16x8*)&Bs[(wc * 64 + j * 16 + l16) * 64 + ac];
#pragma unroll
            for (int i = 0; i < 4; i++)
#pragma unroll
                for (int j = 0; j < 4; j++)
                    acc[i][j] = __builtin_amdgcn_mfma_f32_16x16x32_bf16(af[i], bfv[j], acc[i][j], 0, 0, 0);
        }
    }

    int c[4];
#pragma unroll
    for (int j = 0; j < 4; j++) c[j] = wc * 64 + j * 16 + l16;
#pragma unroll
    for (int i = 0; i < 4; i++) {
#pragma unroll
        for (int r = 0; r < 4; r++) {
            const int rl = i * 16 + quad * 4 + r;
            const size_t grow = (size_t)(m0 + rl) * 256;
            float s = 0.0f, q = 0.0f;
#pragma unroll
            for (int j = 0; j < 4; j++) {
                float v = acc[i][j][r] + entf[grow + c[j]];
                acc[i][j][r] = v;
                s += v;
                q += v * v;
            }
#pragma unroll
            for (int off = 1; off < 16; off <<= 1) {
                s += __shfl_xor(s, off, 64);
                q += __shfl_xor(q, off, 64);
            }
            if (l16 == 0) { red_s[rl * 4 + wc] = s; red_q[rl * 4 + wc] = q; }
        }
    }
    __syncthreads();
#pragma unroll
    for (int i = 0; i < 4; i++) {
#pragma unroll
        for (int r = 0; r < 4; r++) {
            const int rl = i * 16 + quad * 4 + r;
            const size_t grow = (size_t)(m0 + rl) * 256;
            const float4 ss = *(const float4*)&red_s[rl * 4];
            const float4 qq = *(const float4*)&red_q[rl * 4];
            const float S = ss.x + ss.y + ss.z + ss.w;
            const float Q = qq.x + qq.y + qq.z + qq.w;
            const float mu = S * (1.0f / 256.0f);
            const float var = Q * (1.0f / 256.0f) - mu * mu;
            const float rs = rsqrtf(var + 1e-5f);
#pragma unroll
            for (int j = 0; j < 4; j++) {
                const float v = acc[i][j][r];
                yn[grow + c[j]] = f2b((v - mu) * rs * g2[c[j]] + be2[c[j]]);
                xb[grow + c[j]] = f2b(v);
            }
        }
    }
}

// ---------------- fused FF1+FF2 (grid 512, 2 blocks/CU), A-in-registers for G1
#define HSTR 264
__global__ __launch_bounds__(256, 2) void ff_fused(const ushort_t* __restrict__ yn,
                                                   const ushort_t* __restrict__ W1b,
                                                   const ushort_t* __restrict__ W2b,
                                                   const float* __restrict__ bias1,
                                                   const float* __restrict__ bias2,
                                                   const ushort_t* __restrict__ xb,
                                                   float* __restrict__ out) {
    __shared__ __attribute__((aligned(16))) ushort_t Bs[256 * 64];   // 32 KB
    __shared__ __attribute__((aligned(16))) ushort_t Hc[64 * HSTR];  // 33 KB, padded stride

    const int t = threadIdx.x;
    const int m0 = blockIdx.x * 64;
    const int lane = t & 63;
    const int wc = t >> 6;
    const int l16 = lane & 15, quad = lane >> 4;
    const int tr = t >> 3;
    const int csw = (((t & 7) ^ (tr & 7)) << 3);

    f32x4 acc2[4][4];
#pragma unroll
    for (int i = 0; i < 4; i++)
#pragma unroll
        for (int j = 0; j < 4; j++) acc2[i][j] = (f32x4)(0.0f);

    int c4[4];
#pragma unroll
    for (int j = 0; j < 4; j++) c4[j] = wc * 64 + j * 16 + l16;

#pragma unroll 1
    for (int c = 0; c < 8; ++c) {
        f32x4 acc1[4][4];
#pragma unroll
        for (int i = 0; i < 4; i++)
#pragma unroll
            for (int j = 0; j < 4; j++) acc1[i][j] = (f32x4)(0.0f);

        // ---- GEMM1: yn_tile[64x256] @ W1 rows [c*256, c*256+256)
        //      A (yn) comes from global->regs; only W1 panel staged to LDS.
#pragma unroll 1
        for (int kb = 0; kb < 4; ++kb) {
            const int kg = kb * 64;
            __syncthreads();   // prev reads done (kb=0: also GEMM2(c-1) Hc/Bs reads)
#pragma unroll
            for (int p = 0; p < 8; ++p)
                gl2lds16(W1b + (size_t)(c * 256 + p * 32 + tr) * 256 + kg + csw, Bs + p * 2048 + t * 8);
            __syncthreads();   // stage complete & visible
#pragma unroll
            for (int kk = 0; kk < 2; ++kk) {
                const int ank = (((kk << 2) | quad) << 3);                // natural (yn global)
                const int ac  = ((((kk << 2) | quad) ^ (l16 & 7)) << 3);  // swizzled (Bs)
                bf16x8 af[4], bfv[4];
#pragma unroll
                for (int i = 0; i < 4; i++)
                    af[i] = *(const bf16x8*)&yn[(size_t)(m0 + i * 16 + l16) * 256 + kg + ank];
#pragma unroll
                for (int j = 0; j < 4; j++) bfv[j] = *(const bf16x8*)&Bs[(wc * 64 + j * 16 + l16) * 64 + ac];
#pragma unroll
                for (int i = 0; i < 4; i++)
#pragma unroll
                    for (int j = 0; j < 4; j++)
                        acc1[i][j] = __builtin_amdgcn_mfma_f32_16x16x32_bf16(af[i], bfv[j], acc1[i][j], 0, 0, 0);
            }
        }

        // ---- bias1 + relu -> Hc (bf16, padded stride 264, natural cols)
#pragma unroll
        for (int j = 0; j < 4; j++) {
            const float bb = bias1[c * 256 + c4[j]];
#pragma unroll
            for (int i = 0; i < 4; i++) {
                const int rbase = i * 16 + quad * 4;
#pragma unroll
                for (int r = 0; r < 4; r++) {
                    float v = acc1[i][j][r] + bb;
                    v = v > 0.0f ? v : 0.0f;
                    Hc[(rbase + r) * HSTR + c4[j]] = f2b(v);
                }
            }
        }

        // ---- GEMM2: acc2 += Hc[64x256] @ W2 cols [c*256, c*256+256)
#pragma unroll 1
        for (int kb = 0; kb < 4; ++kb) {
            __syncthreads();   // kb=0: publishes Hc + drains G1 Bs reads; kb>0: drains Bs reads
#pragma unroll
            for (int p = 0; p < 8; ++p)
                gl2lds16(W2b + (size_t)(p * 32 + tr) * 2048 + c * 256 + kb * 64 + csw, Bs + p * 2048 + t * 8);
            __syncthreads();   // stage complete & visible
#pragma unroll
            for (int kk = 0; kk < 2; ++kk) {
                const int ank = kb * 64 + (((kk << 2) | quad) << 3);          // natural (Hc, padded)
                const int ac  = ((((kk << 2) | quad) ^ (l16 & 7)) << 3);      // swizzled (Bs)
                bf16x8 af[4], bfv[4];
#pragma unroll
                for (int i = 0; i < 4; i++) af[i]  = *(const bf16x8*)&Hc[(i * 16 + l16) * HSTR + ank];
#pragma unroll
                for (int j = 0; j < 4; j++) bfv[j] = *(const bf16x8*)&Bs[(wc * 64 + j * 16 + l16) * 64 + ac];
#pragma unroll
                for (int i = 0; i < 4; i++)
#pragma unroll
                    for (int j = 0; j < 4; j++)
                        acc2[i][j] = __builtin_amdgcn_mfma_f32_16x16x32_bf16(af[i], bfv[j], acc2[i][j], 0, 0, 0);
            }
        }
    }

    // ---- epilogue: + bias2 + xb residual -> out (f32)
#pragma unroll
    for (int j = 0; j < 4; j++) {
        const float b2 = bias2[c4[j]];
#pragma unroll
        for (int i = 0; i < 4; i++) {
            const int rbase = m0 + i * 16 + quad * 4;
#pragma unroll
            for (int r = 0; r < 4; r++) {
                const size_t o = (size_t)(rbase + r) * 256 + c4[j];
                out[o] = acc2[i][j][r] + b2 + b2f(xb[o]);
            }
        }
    }
}

extern "C" void kernel_launch(void* const* d_in, const int* in_sizes, int n_in,
                              void* d_out, int out_size, void* d_ws, size_t ws_size,
                              hipStream_t stream) {
    const float* ent   = (const float*)d_in[0];
    const float* w_in  = (const float*)d_in[1];
    const float* w_out = (const float*)d_in[2];
    const float* W1    = (const float*)d_in[3];
    const float* bias1 = (const float*)d_in[4];
    const float* W2    = (const float*)d_in[5];
    const float* bias2 = (const float*)d_in[6];
    const float* g1    = (const float*)d_in[7];
    const float* be1   = (const float*)d_in[8];
    const float* g2    = (const float*)d_in[9];
    const float* be2   = (const float*)d_in[10];
    float* out = (float*)d_out;

    char* ws = (char*)d_ws;
    ushort_t* xn     = (ushort_t*)ws;
    ushort_t* yn     = (ushort_t*)(ws + 16777216);
    ushort_t* xb     = (ushort_t*)(ws + 2 * 16777216);
    ushort_t* bt_in  = (ushort_t*)(ws + 3 * 16777216);
    ushort_t* bt_out = bt_in + WELEM;
    ushort_t* W1b    = bt_out + WELEM;
    ushort_t* W2b    = W1b + WELEM;

    // 1) convert + repack weights to bf16
    convert_weights<<<dim3(768), dim3(256), 0, stream>>>(w_in, w_out, W1, W2,
                                                         bt_in, bt_out, W1b, W2b);
    // 2) LN1: ent -> xn (bf16)
    ln_fast<<<dim3(M_SZ / 4), dim3(256), 0, stream>>>(ent, g1, be1, xn);
    // 3) TT gemm + fused LN2 (grid 512, A-in-regs, 4 blocks/CU)
    tt_ln2<<<dim3(M_SZ / 64), dim3(256), 0, stream>>>(xn, bt_in, bt_out, g2, be2, ent, yn, xb);
    // 4) fused FF1+FF2 (grid 512, A-in-regs for G1, 2 blocks/CU)
    ff_fused<<<dim3(M_SZ / 64), dim3(256), 0, stream>>>(yn, W1b, W2b, bias1, bias2, xb, out);
}

// Round 10
// 274.737 us; speedup vs baseline: 1.2122x; 1.2122x over previous
//
#include <hip/hip_runtime.h>
#include <hip/hip_bf16.h>

typedef unsigned short ushort_t;
typedef __attribute__((ext_vector_type(8))) short bf16x8;
typedef __attribute__((ext_vector_type(4))) float f32x4;

#define B_SZ 4096
#define N_SZ 8
#define D_SZ 256
#define FF_SZ 2048
#define M_SZ (B_SZ * N_SZ)   // 32768
#define WELEM (D_SZ * D_SZ * N_SZ)  // 524288

__device__ inline float b2f(ushort_t u) {
    union { unsigned int i; float f; } t; t.i = ((unsigned int)u) << 16; return t.f;
}
__device__ inline ushort_t f2b(float f) {
    union { unsigned int i; float f; } t; t.f = f;
    unsigned int i = t.i;
    unsigned int r = (i + 0x7fffu + ((i >> 16) & 1u)) >> 16;
    return (ushort_t)r;
}

// async global->LDS, 16B per lane; LDS dest must be wave-uniform base + lane*16
__device__ inline void gl2lds16(const ushort_t* g, ushort_t* l) {
    __builtin_amdgcn_global_load_lds((const __attribute__((address_space(1))) void*)g,
                                     (__attribute__((address_space(3))) void*)l, 16, 0, 0);
}

// ---------------- convert/repack all weights f32 -> bf16 (unchanged, proven)
__global__ __launch_bounds__(256) void convert_weights(const float* __restrict__ w_in,
                                                       const float* __restrict__ w_out,
                                                       const float* __restrict__ W1,
                                                       const float* __restrict__ W2,
                                                       ushort_t* __restrict__ bt_in,
                                                       ushort_t* __restrict__ bt_out,
                                                       ushort_t* __restrict__ W1b,
                                                       ushort_t* __restrict__ W2b) {
    __shared__ float tile[64][65];
    const int bid = blockIdx.x;
    const int t = threadIdx.x;
    if (bid < 256) {
        const float* w = (bid < 128) ? w_in : w_out;
        ushort_t* bt = (bid < 128) ? bt_in : bt_out;
        const int id = bid & 127;
        const int d10 = (id >> 5) * 64;
        const int j0  = (id & 31) * 64;
#pragma unroll
        for (int it = 0; it < 16; ++it) {
            const int d1l = it * 4 + (t >> 6);
            const int jl = t & 63;
            tile[d1l][jl] = w[(size_t)(d10 + d1l) * 2048 + j0 + jl];
        }
        __syncthreads();
#pragma unroll
        for (int it = 0; it < 16; ++it) {
            const int jl = it * 4 + (t >> 6);
            const int d1l = t & 63;
            const int j = j0 + jl;
            bt[(size_t)(j >> 3) * 2048 + (j & 7) * 256 + d10 + d1l] = f2b(tile[d1l][jl]);
        }
    } else {
        const int id = bid - 256;
        const float* w = (id < 256) ? W1 : W2;
        ushort_t* o = (id < 256) ? W1b : W2b;
        const size_t base = (size_t)(id & 255) * 2048 + t * 8;
        const float4 a = *(const float4*)&w[base];
        const float4 b = *(const float4*)&w[base + 4];
        *(ushort4*)&o[base]     = make_ushort4(f2b(a.x), f2b(a.y), f2b(a.z), f2b(a.w));
        *(ushort4*)&o[base + 4] = make_ushort4(f2b(b.x), f2b(b.y), f2b(b.z), f2b(b.w));
    }
}

// ---------------- LN1: one WAVE per row of 256 (unchanged, proven)
__global__ __launch_bounds__(256) void ln_fast(const float* __restrict__ xin,
                                               const float* __restrict__ gam,
                                               const float* __restrict__ bet,
                                               ushort_t* __restrict__ out) {
    const int wave = threadIdx.x >> 6;
    const int lane = threadIdx.x & 63;
    const size_t row = (size_t)blockIdx.x * 4 + wave;
    const float4 v = *(const float4*)&xin[row * 256 + lane * 4];
    float s = v.x + v.y + v.z + v.w;
    float q = v.x * v.x + v.y * v.y + v.z * v.z + v.w * v.w;
#pragma unroll
    for (int off = 1; off < 64; off <<= 1) {
        s += __shfl_xor(s, off, 64);
        q += __shfl_xor(q, off, 64);
    }
    const float mu = s * (1.0f / 256.0f);
    const float var = q * (1.0f / 256.0f) - mu * mu;
    const float rs = rsqrtf(var + 1e-5f);
    const float4 g = *(const float4*)&gam[lane * 4];
    const float4 b = *(const float4*)&bet[lane * 4];
    ushort4 o;
    o.x = f2b((v.x - mu) * rs * g.x + b.x);
    o.y = f2b((v.y - mu) * rs * g.y + b.y);
    o.z = f2b((v.z - mu) * rs * g.z + b.z);
    o.w = f2b((v.w - mu) * rs * g.w + b.w);
    *(ushort4*)&out[row * 256 + lane * 4] = o;
}

// ============================================================================
// R19: composition of the two best HARNESS-MEASURED kernels.
//  - tt_ln2_v2: R12 verbatim. Measured 93.4 us (vs ~125 us for the R15 tt):
//    256x256 tile, 512 thr (8 waves, per-wave 128x64), BK=64 dbuf pipeline,
//    0 bank conflicts. Grid 128 (half-chip) -- accepted; every attempt to
//    full-grid it (K-split R16, BK=32 R13, 128-tile R14) measured slower.
//  - ff_fused: R15 verbatim. Measured ~97 us.
// R18 post-mortem: A-from-global regressed (L2 latency, vmcnt-serialized
// before MFMA) -> reverted; this also falsified the "LDS pipe 92% busy" model
// (per-wave issue cost is not CU throughput).
// ============================================================================

// ---------------- TT gemm + fused LN2 (R12 verbatim; grid 128, 512 threads)
__global__ __launch_bounds__(512, 2) void tt_ln2_v2(const ushort_t* __restrict__ A,
                                                    const ushort_t* __restrict__ Bt0,
                                                    const ushort_t* __restrict__ Bt1,
                                                    const float* __restrict__ g2,
                                                    const float* __restrict__ be2,
                                                    const float* __restrict__ entf,
                                                    ushort_t* __restrict__ yn,
                                                    ushort_t* __restrict__ xb) {
    __shared__ __attribute__((aligned(16))) ushort_t As[2][256 * 64];   // 64 KB
    __shared__ __attribute__((aligned(16))) ushort_t Bs[2][256 * 64];   // 64 KB
    __shared__ float red_s[256 * 4];
    __shared__ float red_q[256 * 4];

    const int t = threadIdx.x;
    // even blocks -> first half (Bt0), odd -> second half (Bt1): XCD L2 locality
    const int lb = ((blockIdx.x & 1) << 6) | (blockIdx.x >> 1);
    const int m0 = lb * 256;
    const int lane = t & 63;
    const int wave = t >> 6;
    const int wr = wave >> 2, wc = wave & 3;     // 2 x 4 wave grid, per-wave 128x64
    const int l16 = lane & 15, quad = lane >> 4;
    const int tr = t >> 3;                        // 0..63
    const int csw = (((t & 7) ^ (tr & 7)) << 3);

    const ushort_t* Bt = (m0 >= M_SZ / 2) ? Bt1 : Bt0;

    f32x4 acc[8][4];
#pragma unroll
    for (int i = 0; i < 8; i++)
#pragma unroll
        for (int j = 0; j < 4; j++) acc[i][j] = (f32x4)(0.0f);

    auto stage = [&](int kt) {
        ushort_t* a = As[kt & 1];
        ushort_t* b = Bs[kt & 1];
        const int kg = kt * 64;
#pragma unroll
        for (int p = 0; p < 4; ++p) {
            const int mrow = m0 + p * 64 + tr;
            const int kcol = kg + csw;
            const int s = kcol >> 8;
            const ushort_t* gA = A + (size_t)((mrow & ~7) + (((mrow & 7) - s) & 7)) * 256 + (kcol & 255);
            gl2lds16(gA, a + p * 4096 + t * 8);
        }
#pragma unroll
        for (int p = 0; p < 4; ++p) {
            gl2lds16(Bt + (size_t)(p * 64 + tr) * 2048 + kg + csw, b + p * 4096 + t * 8);
        }
    };

    stage(0);
#pragma unroll 1
    for (int kt = 0; kt < 32; ++kt) {
        __syncthreads();            // drains stage(kt); prior readers of the other buf are done
        if (kt < 31) stage(kt + 1); // DMA overlaps MFMAs below
        const ushort_t* a = As[kt & 1];
        const ushort_t* b = Bs[kt & 1];
#pragma unroll
        for (int kk = 0; kk < 2; ++kk) {
            const int ac = ((((kk << 2) | quad) ^ (l16 & 7)) << 3);
            bf16x8 af[8], bfv[4];
#pragma unroll
            for (int i = 0; i < 8; i++) af[i]  = *(const bf16x8*)&a[(wr * 128 + i * 16 + l16) * 64 + ac];
#pragma unroll
            for (int j = 0; j < 4; j++) bfv[j] = *(const bf16x8*)&b[(wc * 64 + j * 16 + l16) * 64 + ac];
#pragma unroll
            for (int i = 0; i < 8; i++)
#pragma unroll
                for (int j = 0; j < 4; j++)
                    acc[i][j] = __builtin_amdgcn_mfma_f32_16x16x32_bf16(af[i], bfv[j], acc[i][j], 0, 0, 0);
        }
    }

    int c4[4];
#pragma unroll
    for (int j = 0; j < 4; j++) c4[j] = wc * 64 + j * 16 + l16;
#pragma unroll
    for (int i = 0; i < 8; i++) {
#pragma unroll
        for (int r = 0; r < 4; r++) {
            const int rl = wr * 128 + i * 16 + quad * 4 + r;
            const size_t grow = (size_t)(m0 + rl) * 256;
            float s = 0.0f, q = 0.0f;
#pragma unroll
            for (int j = 0; j < 4; j++) {
                float v = acc[i][j][r] + entf[grow + c4[j]];
                acc[i][j][r] = v;
                s += v;
                q += v * v;
            }
#pragma unroll
            for (int off = 1; off < 16; off <<= 1) {
                s += __shfl_xor(s, off, 64);
                q += __shfl_xor(q, off, 64);
            }
            if (l16 == 0) { red_s[rl * 4 + wc] = s; red_q[rl * 4 + wc] = q; }
        }
    }
    __syncthreads();
#pragma unroll
    for (int i = 0; i < 8; i++) {
#pragma unroll
        for (int r = 0; r < 4; r++) {
            const int rl = wr * 128 + i * 16 + quad * 4 + r;
            const size_t grow = (size_t)(m0 + rl) * 256;
            const float4 ss = *(const float4*)&red_s[rl * 4];
            const float4 qq = *(const float4*)&red_q[rl * 4];
            const float S = ss.x + ss.y + ss.z + ss.w;
            const float Q = qq.x + qq.y + qq.z + qq.w;
            const float mu = S * (1.0f / 256.0f);
            const float var = Q * (1.0f / 256.0f) - mu * mu;
            const float rs = rsqrtf(var + 1e-5f);
#pragma unroll
            for (int j = 0; j < 4; j++) {
                const float v = acc[i][j][r];
                yn[grow + c4[j]] = f2b((v - mu) * rs * g2[c4[j]] + be2[c4[j]]);
                xb[grow + c4[j]] = f2b(v);
            }
        }
    }
}

// ---------------- fused FF1+FF2 (R15 verbatim; grid 512, 256 threads)
#define HSTR 264
__global__ __launch_bounds__(256, 2) void ff_fused(const ushort_t* __restrict__ yn,
                                                   const ushort_t* __restrict__ W1b,
                                                   const ushort_t* __restrict__ W2b,
                                                   const float* __restrict__ bias1,
                                                   const float* __restrict__ bias2,
                                                   const ushort_t* __restrict__ xb,
                                                   float* __restrict__ out) {
    __shared__ __attribute__((aligned(16))) ushort_t As[64 * 64];    // 8 KB
    __shared__ __attribute__((aligned(16))) ushort_t Bs[256 * 64];   // 32 KB
    __shared__ __attribute__((aligned(16))) ushort_t Hc[64 * HSTR];  // 33 KB, padded stride

    const int t = threadIdx.x;
    const int m0 = blockIdx.x * 64;
    const int lane = t & 63;
    const int wc = t >> 6;
    const int l16 = lane & 15, quad = lane >> 4;
    const int tr = t >> 3;
    const int csw = (((t & 7) ^ (tr & 7)) << 3);

    f32x4 acc2[4][4];
#pragma unroll
    for (int i = 0; i < 4; i++)
#pragma unroll
        for (int j = 0; j < 4; j++) acc2[i][j] = (f32x4)(0.0f);

    int c4[4];
#pragma unroll
    for (int j = 0; j < 4; j++) c4[j] = wc * 64 + j * 16 + l16;

#pragma unroll 1
    for (int c = 0; c < 8; ++c) {
        f32x4 acc1[4][4];
#pragma unroll
        for (int i = 0; i < 4; i++)
#pragma unroll
            for (int j = 0; j < 4; j++) acc1[i][j] = (f32x4)(0.0f);

        // ---- GEMM1: yn_tile[64x256] @ W1 rows [c*256, c*256+256)
#pragma unroll 1
        for (int kb = 0; kb < 4; ++kb) {
            const int kg = kb * 64;
            __syncthreads();   // prev reads done (kb=0: also GEMM2(c-1) Hc/Bs reads)
#pragma unroll
            for (int p = 0; p < 2; ++p)
                gl2lds16(yn + (size_t)(m0 + p * 32 + tr) * 256 + kg + csw, As + p * 2048 + t * 8);
#pragma unroll
            for (int p = 0; p < 8; ++p)
                gl2lds16(W1b + (size_t)(c * 256 + p * 32 + tr) * 256 + kg + csw, Bs + p * 2048 + t * 8);
            __syncthreads();   // stage complete & visible
#pragma unroll
            for (int kk = 0; kk < 2; ++kk) {
                const int ac = ((((kk << 2) | quad) ^ (l16 & 7)) << 3);
                bf16x8 af[4], bfv[4];
#pragma unroll
                for (int i = 0; i < 4; i++) af[i]  = *(const bf16x8*)&As[(i * 16 + l16) * 64 + ac];
#pragma unroll
                for (int j = 0; j < 4; j++) bfv[j] = *(const bf16x8*)&Bs[(wc * 64 + j * 16 + l16) * 64 + ac];
#pragma unroll
                for (int i = 0; i < 4; i++)
#pragma unroll
                    for (int j = 0; j < 4; j++)
                        acc1[i][j] = __builtin_amdgcn_mfma_f32_16x16x32_bf16(af[i], bfv[j], acc1[i][j], 0, 0, 0);
            }
        }

        // ---- bias1 + relu -> Hc (bf16, padded stride 264, natural cols)
#pragma unroll
        for (int j = 0; j < 4; j++) {
            const float bb = bias1[c * 256 + c4[j]];
#pragma unroll
            for (int i = 0; i < 4; i++) {
                const int rbase = i * 16 + quad * 4;
#pragma unroll
                for (int r = 0; r < 4; r++) {
                    float v = acc1[i][j][r] + bb;
                    v = v > 0.0f ? v : 0.0f;
                    Hc[(rbase + r) * HSTR + c4[j]] = f2b(v);
                }
            }
        }

        // ---- GEMM2: acc2 += Hc[64x256] @ W2 cols [c*256, c*256+256)
#pragma unroll 1
        for (int kb = 0; kb < 4; ++kb) {
            __syncthreads();   // kb=0: publishes Hc + drains G1 Bs reads; kb>0: drains Bs reads
#pragma unroll
            for (int p = 0; p < 8; ++p)
                gl2lds16(W2b + (size_t)(p * 32 + tr) * 2048 + c * 256 + kb * 64 + csw, Bs + p * 2048 + t * 8);
            __syncthreads();   // stage complete & visible
#pragma unroll
            for (int kk = 0; kk < 2; ++kk) {
                const int ank = kb * 64 + (((kk << 2) | quad) << 3);          // natural (Hc, padded)
                const int ac  = ((((kk << 2) | quad) ^ (l16 & 7)) << 3);      // swizzled (Bs)
                bf16x8 af[4], bfv[4];
#pragma unroll
                for (int i = 0; i < 4; i++) af[i]  = *(const bf16x8*)&Hc[(i * 16 + l16) * HSTR + ank];
#pragma unroll
                for (int j = 0; j < 4; j++) bfv[j] = *(const bf16x8*)&Bs[(wc * 64 + j * 16 + l16) * 64 + ac];
#pragma unroll
                for (int i = 0; i < 4; i++)
#pragma unroll
                    for (int j = 0; j < 4; j++)
                        acc2[i][j] = __builtin_amdgcn_mfma_f32_16x16x32_bf16(af[i], bfv[j], acc2[i][j], 0, 0, 0);
            }
        }
    }

    // ---- epilogue: + bias2 + xb residual -> out (f32)
#pragma unroll
    for (int j = 0; j < 4; j++) {
        const float b2 = bias2[c4[j]];
#pragma unroll
        for (int i = 0; i < 4; i++) {
            const int rbase = m0 + i * 16 + quad * 4;
#pragma unroll
            for (int r = 0; r < 4; r++) {
                const size_t o = (size_t)(rbase + r) * 256 + c4[j];
                out[o] = acc2[i][j][r] + b2 + b2f(xb[o]);
            }
        }
    }
}

extern "C" void kernel_launch(void* const* d_in, const int* in_sizes, int n_in,
                              void* d_out, int out_size, void* d_ws, size_t ws_size,
                              hipStream_t stream) {
    const float* ent   = (const float*)d_in[0];
    const float* w_in  = (const float*)d_in[1];
    const float* w_out = (const float*)d_in[2];
    const float* W1    = (const float*)d_in[3];
    const float* bias1 = (const float*)d_in[4];
    const float* W2    = (const float*)d_in[5];
    const float* bias2 = (const float*)d_in[6];
    const float* g1    = (const float*)d_in[7];
    const float* be1   = (const float*)d_in[8];
    const float* g2    = (const float*)d_in[9];
    const float* be2   = (const float*)d_in[10];
    float* out = (float*)d_out;

    char* ws = (char*)d_ws;
    ushort_t* xn     = (ushort_t*)ws;
    ushort_t* yn     = (ushort_t*)(ws + 16777216);
    ushort_t* xb     = (ushort_t*)(ws + 2 * 16777216);
    ushort_t* bt_in  = (ushort_t*)(ws + 3 * 16777216);
    ushort_t* bt_out = bt_in + WELEM;
    ushort_t* W1b    = bt_out + WELEM;
    ushort_t* W2b    = W1b + WELEM;

    // 1) convert + repack weights to bf16
    convert_weights<<<dim3(768), dim3(256), 0, stream>>>(w_in, w_out, W1, W2,
                                                         bt_in, bt_out, W1b, W2b);
    // 2) LN1: ent -> xn (bf16)
    ln_fast<<<dim3(M_SZ / 4), dim3(256), 0, stream>>>(ent, g1, be1, xn);
    // 3) TT gemm + fused LN2 (R12 verbatim: 256-tile, measured 93.4 us)
    tt_ln2_v2<<<dim3(M_SZ / 256), dim3(512), 0, stream>>>(xn, bt_in, bt_out, g2, be2, ent, yn, xb);
    // 4) fused FF1+FF2 (R15 verbatim: measured ~97 us)
    ff_fused<<<dim3(M_SZ / 64), dim3(256), 0, stream>>>(yn, W1b, W2b, bias1, bias2, xb, out);
}

// Round 11
// 241.715 us; speedup vs baseline: 1.3778x; 1.1366x over previous
//
#include <hip/hip_runtime.h>
#include <hip/hip_bf16.h>

typedef unsigned short ushort_t;
typedef __attribute__((ext_vector_type(8))) short bf16x8;
typedef __attribute__((ext_vector_type(4))) float f32x4;

#define B_SZ 4096
#define N_SZ 8
#define D_SZ 256
#define FF_SZ 2048
#define M_SZ (B_SZ * N_SZ)   // 32768
#define WELEM (D_SZ * D_SZ * N_SZ)  // 524288

__device__ inline float b2f(ushort_t u) {
    union { unsigned int i; float f; } t; t.i = ((unsigned int)u) << 16; return t.f;
}
__device__ inline ushort_t f2b(float f) {
    union { unsigned int i; float f; } t; t.f = f;
    unsigned int i = t.i;
    unsigned int r = (i + 0x7fffu + ((i >> 16) & 1u)) >> 16;
    return (ushort_t)r;
}

// async global->LDS, 16B per lane; LDS dest must be wave-uniform base + lane*16
__device__ inline void gl2lds16(const ushort_t* g, ushort_t* l) {
    __builtin_amdgcn_global_load_lds((const __attribute__((address_space(1))) void*)g,
                                     (__attribute__((address_space(3))) void*)l, 16, 0, 0);
}

// ---------------- prep: convert/repack weights (blocks 0..767) + LN1 (768..8959)
// R20: merged from the two proven kernels verbatim -- removes one launch
// boundary and co-schedules convert's short 768-block tail with LN's 8192
// blocks. Branch is uniform per block; __syncthreads only in convert branch.
__global__ __launch_bounds__(256) void prep(const float* __restrict__ w_in,
                                            const float* __restrict__ w_out,
                                            const float* __restrict__ W1,
                                            const float* __restrict__ W2,
                                            ushort_t* __restrict__ bt_in,
                                            ushort_t* __restrict__ bt_out,
                                            ushort_t* __restrict__ W1b,
                                            ushort_t* __restrict__ W2b,
                                            const float* __restrict__ xin,
                                            const float* __restrict__ gam,
                                            const float* __restrict__ bet,
                                            ushort_t* __restrict__ xnout) {
    __shared__ float tile[64][65];
    const int bid = blockIdx.x;
    const int t = threadIdx.x;
    if (bid < 256) {
        const float* w = (bid < 128) ? w_in : w_out;
        ushort_t* bt = (bid < 128) ? bt_in : bt_out;
        const int id = bid & 127;
        const int d10 = (id >> 5) * 64;
        const int j0  = (id & 31) * 64;
#pragma unroll
        for (int it = 0; it < 16; ++it) {
            const int d1l = it * 4 + (t >> 6);
            const int jl = t & 63;
            tile[d1l][jl] = w[(size_t)(d10 + d1l) * 2048 + j0 + jl];
        }
        __syncthreads();
#pragma unroll
        for (int it = 0; it < 16; ++it) {
            const int jl = it * 4 + (t >> 6);
            const int d1l = t & 63;
            const int j = j0 + jl;
            bt[(size_t)(j >> 3) * 2048 + (j & 7) * 256 + d10 + d1l] = f2b(tile[d1l][jl]);
        }
    } else if (bid < 768) {
        const int id = bid - 256;
        const float* w = (id < 256) ? W1 : W2;
        ushort_t* o = (id < 256) ? W1b : W2b;
        const size_t base = (size_t)(id & 255) * 2048 + t * 8;
        const float4 a = *(const float4*)&w[base];
        const float4 b = *(const float4*)&w[base + 4];
        *(ushort4*)&o[base]     = make_ushort4(f2b(a.x), f2b(a.y), f2b(a.z), f2b(a.w));
        *(ushort4*)&o[base + 4] = make_ushort4(f2b(b.x), f2b(b.y), f2b(b.z), f2b(b.w));
    } else {
        const int wave = t >> 6;
        const int lane = t & 63;
        const size_t row = (size_t)(bid - 768) * 4 + wave;
        const float4 v = *(const float4*)&xin[row * 256 + lane * 4];
        float s = v.x + v.y + v.z + v.w;
        float q = v.x * v.x + v.y * v.y + v.z * v.z + v.w * v.w;
#pragma unroll
        for (int off = 1; off < 64; off <<= 1) {
            s += __shfl_xor(s, off, 64);
            q += __shfl_xor(q, off, 64);
        }
        const float mu = s * (1.0f / 256.0f);
        const float var = q * (1.0f / 256.0f) - mu * mu;
        const float rs = rsqrtf(var + 1e-5f);
        const float4 g = *(const float4*)&gam[lane * 4];
        const float4 b = *(const float4*)&bet[lane * 4];
        ushort4 o;
        o.x = f2b((v.x - mu) * rs * g.x + b.x);
        o.y = f2b((v.y - mu) * rs * g.y + b.y);
        o.z = f2b((v.z - mu) * rs * g.z + b.z);
        o.w = f2b((v.w - mu) * rs * g.w + b.w);
        *(ushort4*)&xnout[row * 256 + lane * 4] = o;
    }
}

// ---------------- TT gemm + fused LN2 (R15 verbatim; best e2e config, 241.9 us)
__global__ __launch_bounds__(256, 2) void tt_ln2(const ushort_t* __restrict__ A,
                                                 const ushort_t* __restrict__ Bt0,
                                                 const ushort_t* __restrict__ Bt1,
                                                 const float* __restrict__ g2,
                                                 const float* __restrict__ be2,
                                                 const float* __restrict__ entf,
                                                 ushort_t* __restrict__ yn,
                                                 ushort_t* __restrict__ xb) {
    __shared__ __attribute__((aligned(16))) ushort_t As[64 * 64];    // 8 KB
    __shared__ __attribute__((aligned(16))) ushort_t Bs[256 * 64];   // 32 KB
    __shared__ float red_s[64 * 4];
    __shared__ float red_q[64 * 4];

    const int t = threadIdx.x;
    const int lb = ((blockIdx.x & 1) << 8) | (blockIdx.x >> 1);
    const int m0 = lb * 64;
    const int lane = t & 63;
    const int wc = t >> 6;
    const int l16 = lane & 15, quad = lane >> 4;
    const int tr = t >> 3;
    const int csw = (((t & 7) ^ (tr & 7)) << 3);

    const ushort_t* Bt = (m0 >= M_SZ / 2) ? Bt1 : Bt0;

    f32x4 acc[4][4];
#pragma unroll
    for (int i = 0; i < 4; i++)
#pragma unroll
        for (int j = 0; j < 4; j++) acc[i][j] = (f32x4)(0.0f);

#pragma unroll 1
    for (int kt = 0; kt < 32; ++kt) {
        const int kg = kt * 64;
        __syncthreads();
#pragma unroll
        for (int p = 0; p < 2; ++p) {
            const int mrow = m0 + p * 32 + tr;
            const int kcol = kg + csw;
            const int s = kcol >> 8;
            const ushort_t* gA = A + (size_t)((mrow & ~7) + (((mrow & 7) - s) & 7)) * 256 + (kcol & 255);
            gl2lds16(gA, As + p * 2048 + t * 8);
        }
#pragma unroll
        for (int p = 0; p < 8; ++p) {
            gl2lds16(Bt + (size_t)(p * 32 + tr) * 2048 + kg + csw, Bs + p * 2048 + t * 8);
        }
        __syncthreads();

#pragma unroll
        for (int kk = 0; kk < 2; ++kk) {
            const int ac = ((((kk << 2) | quad) ^ (l16 & 7)) << 3);
            bf16x8 af[4], bfv[4];
#pragma unroll
            for (int i = 0; i < 4; i++) af[i]  = *(const bf16x8*)&As[(i * 16 + l16) * 64 + ac];
#pragma unroll
            for (int j = 0; j < 4; j++) bfv[j] = *(const bf16x8*)&Bs[(wc * 64 + j * 16 + l16) * 64 + ac];
#pragma unroll
            for (int i = 0; i < 4; i++)
#pragma unroll
                for (int j = 0; j < 4; j++)
                    acc[i][j] = __builtin_amdgcn_mfma_f32_16x16x32_bf16(af[i], bfv[j], acc[i][j], 0, 0, 0);
        }
    }

    int c[4];
#pragma unroll
    for (int j = 0; j < 4; j++) c[j] = wc * 64 + j * 16 + l16;
#pragma unroll
    for (int i = 0; i < 4; i++) {
#pragma unroll
        for (int r = 0; r < 4; r++) {
            const int rl = i * 16 + quad * 4 + r;
            const size_t grow = (size_t)(m0 + rl) * 256;
            float s = 0.0f, q = 0.0f;
#pragma unroll
            for (int j = 0; j < 4; j++) {
                float v = acc[i][j][r] + entf[grow + c[j]];
                acc[i][j][r] = v;
                s += v;
                q += v * v;
            }
#pragma unroll
            for (int off = 1; off < 16; off <<= 1) {
                s += __shfl_xor(s, off, 64);
                q += __shfl_xor(q, off, 64);
            }
            if (l16 == 0) { red_s[rl * 4 + wc] = s; red_q[rl * 4 + wc] = q; }
        }
    }
    __syncthreads();
#pragma unroll
    for (int i = 0; i < 4; i++) {
#pragma unroll
        for (int r = 0; r < 4; r++) {
            const int rl = i * 16 + quad * 4 + r;
            const size_t grow = (size_t)(m0 + rl) * 256;
            const float4 ss = *(const float4*)&red_s[rl * 4];
            const float4 qq = *(const float4*)&red_q[rl * 4];
            const float S = ss.x + ss.y + ss.z + ss.w;
            const float Q = qq.x + qq.y + qq.z + qq.w;
            const float mu = S * (1.0f / 256.0f);
            const float var = Q * (1.0f / 256.0f) - mu * mu;
            const float rs = rsqrtf(var + 1e-5f);
#pragma unroll
            for (int j = 0; j < 4; j++) {
                const float v = acc[i][j][r];
                yn[grow + c[j]] = f2b((v - mu) * rs * g2[c[j]] + be2[c[j]]);
                xb[grow + c[j]] = f2b(v);
            }
        }
    }
}

// ---------------- fused FF1+FF2 (R15 verbatim)
#define HSTR 264
__global__ __launch_bounds__(256, 2) void ff_fused(const ushort_t* __restrict__ yn,
                                                   const ushort_t* __restrict__ W1b,
                                                   const ushort_t* __restrict__ W2b,
                                                   const float* __restrict__ bias1,
                                                   const float* __restrict__ bias2,
                                                   const ushort_t* __restrict__ xb,
                                                   float* __restrict__ out) {
    __shared__ __attribute__((aligned(16))) ushort_t As[64 * 64];    // 8 KB
    __shared__ __attribute__((aligned(16))) ushort_t Bs[256 * 64];   // 32 KB
    __shared__ __attribute__((aligned(16))) ushort_t Hc[64 * HSTR];  // 33 KB, padded stride

    const int t = threadIdx.x;
    const int m0 = blockIdx.x * 64;
    const int lane = t & 63;
    const int wc = t >> 6;
    const int l16 = lane & 15, quad = lane >> 4;
    const int tr = t >> 3;
    const int csw = (((t & 7) ^ (tr & 7)) << 3);

    f32x4 acc2[4][4];
#pragma unroll
    for (int i = 0; i < 4; i++)
#pragma unroll
        for (int j = 0; j < 4; j++) acc2[i][j] = (f32x4)(0.0f);

    int c4[4];
#pragma unroll
    for (int j = 0; j < 4; j++) c4[j] = wc * 64 + j * 16 + l16;

#pragma unroll 1
    for (int c = 0; c < 8; ++c) {
        f32x4 acc1[4][4];
#pragma unroll
        for (int i = 0; i < 4; i++)
#pragma unroll
            for (int j = 0; j < 4; j++) acc1[i][j] = (f32x4)(0.0f);

        // ---- GEMM1: yn_tile[64x256] @ W1 rows [c*256, c*256+256)
#pragma unroll 1
        for (int kb = 0; kb < 4; ++kb) {
            const int kg = kb * 64;
            __syncthreads();   // prev reads done (kb=0: also GEMM2(c-1) Hc/Bs reads)
#pragma unroll
            for (int p = 0; p < 2; ++p)
                gl2lds16(yn + (size_t)(m0 + p * 32 + tr) * 256 + kg + csw, As + p * 2048 + t * 8);
#pragma unroll
            for (int p = 0; p < 8; ++p)
                gl2lds16(W1b + (size_t)(c * 256 + p * 32 + tr) * 256 + kg + csw, Bs + p * 2048 + t * 8);
            __syncthreads();   // stage complete & visible
#pragma unroll
            for (int kk = 0; kk < 2; ++kk) {
                const int ac = ((((kk << 2) | quad) ^ (l16 & 7)) << 3);
                bf16x8 af[4], bfv[4];
#pragma unroll
                for (int i = 0; i < 4; i++) af[i]  = *(const bf16x8*)&As[(i * 16 + l16) * 64 + ac];
#pragma unroll
                for (int j = 0; j < 4; j++) bfv[j] = *(const bf16x8*)&Bs[(wc * 64 + j * 16 + l16) * 64 + ac];
#pragma unroll
                for (int i = 0; i < 4; i++)
#pragma unroll
                    for (int j = 0; j < 4; j++)
                        acc1[i][j] = __builtin_amdgcn_mfma_f32_16x16x32_bf16(af[i], bfv[j], acc1[i][j], 0, 0, 0);
            }
        }

        // ---- bias1 + relu -> Hc (bf16, padded stride 264, natural cols)
#pragma unroll
        for (int j = 0; j < 4; j++) {
            const float bb = bias1[c * 256 + c4[j]];
#pragma unroll
            for (int i = 0; i < 4; i++) {
                const int rbase = i * 16 + quad * 4;
#pragma unroll
                for (int r = 0; r < 4; r++) {
                    float v = acc1[i][j][r] + bb;
                    v = v > 0.0f ? v : 0.0f;
                    Hc[(rbase + r) * HSTR + c4[j]] = f2b(v);
                }
            }
        }

        // ---- GEMM2: acc2 += Hc[64x256] @ W2 cols [c*256, c*256+256)
#pragma unroll 1
        for (int kb = 0; kb < 4; ++kb) {
            __syncthreads();   // kb=0: publishes Hc + drains G1 Bs reads; kb>0: drains Bs reads
#pragma unroll
            for (int p = 0; p < 8; ++p)
                gl2lds16(W2b + (size_t)(p * 32 + tr) * 2048 + c * 256 + kb * 64 + csw, Bs + p * 2048 + t * 8);
            __syncthreads();   // stage complete & visible
#pragma unroll
            for (int kk = 0; kk < 2; ++kk) {
                const int ank = kb * 64 + (((kk << 2) | quad) << 3);          // natural (Hc, padded)
                const int ac  = ((((kk << 2) | quad) ^ (l16 & 7)) << 3);      // swizzled (Bs)
                bf16x8 af[4], bfv[4];
#pragma unroll
                for (int i = 0; i < 4; i++) af[i]  = *(const bf16x8*)&Hc[(i * 16 + l16) * HSTR + ank];
#pragma unroll
                for (int j = 0; j < 4; j++) bfv[j] = *(const bf16x8*)&Bs[(wc * 64 + j * 16 + l16) * 64 + ac];
#pragma unroll
                for (int i = 0; i < 4; i++)
#pragma unroll
                    for (int j = 0; j < 4; j++)
                        acc2[i][j] = __builtin_amdgcn_mfma_f32_16x16x32_bf16(af[i], bfv[j], acc2[i][j], 0, 0, 0);
            }
        }
    }

    // ---- epilogue: + bias2 + xb residual -> out (f32)
#pragma unroll
    for (int j = 0; j < 4; j++) {
        const float b2 = bias2[c4[j]];
#pragma unroll
        for (int i = 0; i < 4; i++) {
            const int rbase = m0 + i * 16 + quad * 4;
#pragma unroll
            for (int r = 0; r < 4; r++) {
                const size_t o = (size_t)(rbase + r) * 256 + c4[j];
                out[o] = acc2[i][j][r] + b2 + b2f(xb[o]);
            }
        }
    }
}

extern "C" void kernel_launch(void* const* d_in, const int* in_sizes, int n_in,
                              void* d_out, int out_size, void* d_ws, size_t ws_size,
                              hipStream_t stream) {
    const float* ent   = (const float*)d_in[0];
    const float* w_in  = (const float*)d_in[1];
    const float* w_out = (const float*)d_in[2];
    const float* W1    = (const float*)d_in[3];
    const float* bias1 = (const float*)d_in[4];
    const float* W2    = (const float*)d_in[5];
    const float* bias2 = (const float*)d_in[6];
    const float* g1    = (const float*)d_in[7];
    const float* be1   = (const float*)d_in[8];
    const float* g2    = (const float*)d_in[9];
    const float* be2   = (const float*)d_in[10];
    float* out = (float*)d_out;

    char* ws = (char*)d_ws;
    ushort_t* xn     = (ushort_t*)ws;
    ushort_t* yn     = (ushort_t*)(ws + 16777216);
    ushort_t* xb     = (ushort_t*)(ws + 2 * 16777216);
    ushort_t* bt_in  = (ushort_t*)(ws + 3 * 16777216);
    ushort_t* bt_out = bt_in + WELEM;
    ushort_t* W1b    = bt_out + WELEM;
    ushort_t* W2b    = W1b + WELEM;

    // 1) merged prep: weights->bf16 repack (768 blocks) + LN1 (8192 blocks)
    prep<<<dim3(8960), dim3(256), 0, stream>>>(w_in, w_out, W1, W2,
                                               bt_in, bt_out, W1b, W2b,
                                               ent, g1, be1, xn);
    // 2) TT gemm + fused LN2 (R15 verbatim, grid 512)
    tt_ln2<<<dim3(M_SZ / 64), dim3(256), 0, stream>>>(xn, bt_in, bt_out, g2, be2, ent, yn, xb);
    // 3) fused FF1+FF2 (R15 verbatim, grid 512)
    ff_fused<<<dim3(M_SZ / 64), dim3(256), 0, stream>>>(yn, W1b, W2b, bias1, bias2, xb, out);
}

// Round 12
// 234.634 us; speedup vs baseline: 1.4194x; 1.0302x over previous
//
#include <hip/hip_runtime.h>
#include <hip/hip_bf16.h>

typedef unsigned short ushort_t;
typedef __attribute__((ext_vector_type(8))) short bf16x8;
typedef __attribute__((ext_vector_type(4))) float f32x4;

#define B_SZ 4096
#define N_SZ 8
#define D_SZ 256
#define FF_SZ 2048
#define M_SZ (B_SZ * N_SZ)   // 32768
#define WELEM (D_SZ * D_SZ * N_SZ)  // 524288

__device__ inline float b2f(ushort_t u) {
    union { unsigned int i; float f; } t; t.i = ((unsigned int)u) << 16; return t.f;
}
__device__ inline ushort_t f2b(float f) {
    union { unsigned int i; float f; } t; t.f = f;
    unsigned int i = t.i;
    unsigned int r = (i + 0x7fffu + ((i >> 16) & 1u)) >> 16;
    return (ushort_t)r;
}

// async global->LDS, 16B per lane; LDS dest must be wave-uniform base + lane*16
__device__ inline void gl2lds16(const ushort_t* g, ushort_t* l) {
    __builtin_amdgcn_global_load_lds((const __attribute__((address_space(1))) void*)g,
                                     (__attribute__((address_space(3))) void*)l, 16, 0, 0);
}

// ---------------- prep: convert/repack weights (blocks 0..767) + LN1 (768..8959)
// (R20 verbatim -- measured neutral-positive vs separate launches)
__global__ __launch_bounds__(256) void prep(const float* __restrict__ w_in,
                                            const float* __restrict__ w_out,
                                            const float* __restrict__ W1,
                                            const float* __restrict__ W2,
                                            ushort_t* __restrict__ bt_in,
                                            ushort_t* __restrict__ bt_out,
                                            ushort_t* __restrict__ W1b,
                                            ushort_t* __restrict__ W2b,
                                            const float* __restrict__ xin,
                                            const float* __restrict__ gam,
                                            const float* __restrict__ bet,
                                            ushort_t* __restrict__ xnout) {
    __shared__ float tile[64][65];
    const int bid = blockIdx.x;
    const int t = threadIdx.x;
    if (bid < 256) {
        const float* w = (bid < 128) ? w_in : w_out;
        ushort_t* bt = (bid < 128) ? bt_in : bt_out;
        const int id = bid & 127;
        const int d10 = (id >> 5) * 64;
        const int j0  = (id & 31) * 64;
#pragma unroll
        for (int it = 0; it < 16; ++it) {
            const int d1l = it * 4 + (t >> 6);
            const int jl = t & 63;
            tile[d1l][jl] = w[(size_t)(d10 + d1l) * 2048 + j0 + jl];
        }
        __syncthreads();
#pragma unroll
        for (int it = 0; it < 16; ++it) {
            const int jl = it * 4 + (t >> 6);
            const int d1l = t & 63;
            const int j = j0 + jl;
            bt[(size_t)(j >> 3) * 2048 + (j & 7) * 256 + d10 + d1l] = f2b(tile[d1l][jl]);
        }
    } else if (bid < 768) {
        const int id = bid - 256;
        const float* w = (id < 256) ? W1 : W2;
        ushort_t* o = (id < 256) ? W1b : W2b;
        const size_t base = (size_t)(id & 255) * 2048 + t * 8;
        const float4 a = *(const float4*)&w[base];
        const float4 b = *(const float4*)&w[base + 4];
        *(ushort4*)&o[base]     = make_ushort4(f2b(a.x), f2b(a.y), f2b(a.z), f2b(a.w));
        *(ushort4*)&o[base + 4] = make_ushort4(f2b(b.x), f2b(b.y), f2b(b.z), f2b(b.w));
    } else {
        const int wave = t >> 6;
        const int lane = t & 63;
        const size_t row = (size_t)(bid - 768) * 4 + wave;
        const float4 v = *(const float4*)&xin[row * 256 + lane * 4];
        float s = v.x + v.y + v.z + v.w;
        float q = v.x * v.x + v.y * v.y + v.z * v.z + v.w * v.w;
#pragma unroll
        for (int off = 1; off < 64; off <<= 1) {
            s += __shfl_xor(s, off, 64);
            q += __shfl_xor(q, off, 64);
        }
        const float mu = s * (1.0f / 256.0f);
        const float var = q * (1.0f / 256.0f) - mu * mu;
        const float rs = rsqrtf(var + 1e-5f);
        const float4 g = *(const float4*)&gam[lane * 4];
        const float4 b = *(const float4*)&bet[lane * 4];
        ushort4 o;
        o.x = f2b((v.x - mu) * rs * g.x + b.x);
        o.y = f2b((v.y - mu) * rs * g.y + b.y);
        o.z = f2b((v.z - mu) * rs * g.z + b.z);
        o.w = f2b((v.w - mu) * rs * g.w + b.w);
        *(ushort4*)&xnout[row * 256 + lane * 4] = o;
    }
}

// ============================================================================
// R21 tt_ff: single-kernel fusion of the R15 tt_ln2 + ff_fused bodies.
// Legality: ff for row-stripe m0 reads ONLY yn[m0..m0+64], xb[m0..m0+64]
// (LN2 is row-local) + global weights -- exactly what THIS block's tt phase
// produced. Zero cross-block dependencies; the kernel boundary was pure
// overhead (~30 us of e2e lives between dispatches; R19 showed rocprof
// per-kernel times don't capture it).
// Phase boundary: __syncthreads drains vmcnt (yn/xb stores complete) before
// the ff phase's first gl2lds16 reads them back -- same-CU L2, coherent+hot.
// LDS: As 8K + Bs 32K + Hc 33K + red 2K = 75 KB -> 2 blocks/CU preserved.
// Bodies are byte-identical to the 241.7-us-verified R15/R20 kernels.
// ============================================================================
#define HSTR 264
__global__ __launch_bounds__(256, 2) void tt_ff(const ushort_t* __restrict__ A,
                                                const ushort_t* __restrict__ Bt0,
                                                const ushort_t* __restrict__ Bt1,
                                                const float* __restrict__ g2,
                                                const float* __restrict__ be2,
                                                const float* __restrict__ entf,
                                                const ushort_t* __restrict__ W1b,
                                                const ushort_t* __restrict__ W2b,
                                                const float* __restrict__ bias1,
                                                const float* __restrict__ bias2,
                                                ushort_t* __restrict__ yn,
                                                ushort_t* __restrict__ xb,
                                                float* __restrict__ out) {
    __shared__ __attribute__((aligned(16))) ushort_t As[64 * 64];    // 8 KB
    __shared__ __attribute__((aligned(16))) ushort_t Bs[256 * 64];   // 32 KB
    __shared__ __attribute__((aligned(16))) ushort_t Hc[64 * HSTR];  // 33 KB (ff phase)
    __shared__ float red_s[64 * 4];
    __shared__ float red_q[64 * 4];

    const int t = threadIdx.x;
    const int lb = ((blockIdx.x & 1) << 8) | (blockIdx.x >> 1);
    const int m0 = lb * 64;
    const int lane = t & 63;
    const int wc = t >> 6;
    const int l16 = lane & 15, quad = lane >> 4;
    const int tr = t >> 3;
    const int csw = (((t & 7) ^ (tr & 7)) << 3);

    int c4[4];
#pragma unroll
    for (int j = 0; j < 4; j++) c4[j] = wc * 64 + j * 16 + l16;

    // ========================= PHASE 1: TT gemm + LN2 =========================
    {
        const ushort_t* Bt = (m0 >= M_SZ / 2) ? Bt1 : Bt0;

        f32x4 acc[4][4];
#pragma unroll
        for (int i = 0; i < 4; i++)
#pragma unroll
            for (int j = 0; j < 4; j++) acc[i][j] = (f32x4)(0.0f);

#pragma unroll 1
        for (int kt = 0; kt < 32; ++kt) {
            const int kg = kt * 64;
            __syncthreads();
#pragma unroll
            for (int p = 0; p < 2; ++p) {
                const int mrow = m0 + p * 32 + tr;
                const int kcol = kg + csw;
                const int s = kcol >> 8;
                const ushort_t* gA = A + (size_t)((mrow & ~7) + (((mrow & 7) - s) & 7)) * 256 + (kcol & 255);
                gl2lds16(gA, As + p * 2048 + t * 8);
            }
#pragma unroll
            for (int p = 0; p < 8; ++p) {
                gl2lds16(Bt + (size_t)(p * 32 + tr) * 2048 + kg + csw, Bs + p * 2048 + t * 8);
            }
            __syncthreads();

#pragma unroll
            for (int kk = 0; kk < 2; ++kk) {
                const int ac = ((((kk << 2) | quad) ^ (l16 & 7)) << 3);
                bf16x8 af[4], bfv[4];
#pragma unroll
                for (int i = 0; i < 4; i++) af[i]  = *(const bf16x8*)&As[(i * 16 + l16) * 64 + ac];
#pragma unroll
                for (int j = 0; j < 4; j++) bfv[j] = *(const bf16x8*)&Bs[(wc * 64 + j * 16 + l16) * 64 + ac];
#pragma unroll
                for (int i = 0; i < 4; i++)
#pragma unroll
                    for (int j = 0; j < 4; j++)
                        acc[i][j] = __builtin_amdgcn_mfma_f32_16x16x32_bf16(af[i], bfv[j], acc[i][j], 0, 0, 0);
            }
        }

#pragma unroll
        for (int i = 0; i < 4; i++) {
#pragma unroll
            for (int r = 0; r < 4; r++) {
                const int rl = i * 16 + quad * 4 + r;
                const size_t grow = (size_t)(m0 + rl) * 256;
                float s = 0.0f, q = 0.0f;
#pragma unroll
                for (int j = 0; j < 4; j++) {
                    float v = acc[i][j][r] + entf[grow + c4[j]];
                    acc[i][j][r] = v;
                    s += v;
                    q += v * v;
                }
#pragma unroll
                for (int off = 1; off < 16; off <<= 1) {
                    s += __shfl_xor(s, off, 64);
                    q += __shfl_xor(q, off, 64);
                }
                if (l16 == 0) { red_s[rl * 4 + wc] = s; red_q[rl * 4 + wc] = q; }
            }
        }
        __syncthreads();
#pragma unroll
        for (int i = 0; i < 4; i++) {
#pragma unroll
            for (int r = 0; r < 4; r++) {
                const int rl = i * 16 + quad * 4 + r;
                const size_t grow = (size_t)(m0 + rl) * 256;
                const float4 ss = *(const float4*)&red_s[rl * 4];
                const float4 qq = *(const float4*)&red_q[rl * 4];
                const float S = ss.x + ss.y + ss.z + ss.w;
                const float Q = qq.x + qq.y + qq.z + qq.w;
                const float mu = S * (1.0f / 256.0f);
                const float var = Q * (1.0f / 256.0f) - mu * mu;
                const float rs = rsqrtf(var + 1e-5f);
#pragma unroll
                for (int j = 0; j < 4; j++) {
                    const float v = acc[i][j][r];
                    yn[grow + c4[j]] = f2b((v - mu) * rs * g2[c4[j]] + be2[c4[j]]);
                    xb[grow + c4[j]] = f2b(v);
                }
            }
        }
    }
    // phase-1 acc dies here; ff's first __syncthreads (c=0,kb=0) drains the
    // yn/xb stores before the stage reads them back (same-CU L2).

    // ========================= PHASE 2: fused FF1+FF2 =========================
    f32x4 acc2[4][4];
#pragma unroll
    for (int i = 0; i < 4; i++)
#pragma unroll
        for (int j = 0; j < 4; j++) acc2[i][j] = (f32x4)(0.0f);

#pragma unroll 1
    for (int c = 0; c < 8; ++c) {
        f32x4 acc1[4][4];
#pragma unroll
        for (int i = 0; i < 4; i++)
#pragma unroll
            for (int j = 0; j < 4; j++) acc1[i][j] = (f32x4)(0.0f);

        // ---- GEMM1: yn_tile[64x256] @ W1 rows [c*256, c*256+256)
#pragma unroll 1
        for (int kb = 0; kb < 4; ++kb) {
            const int kg = kb * 64;
            __syncthreads();   // prev reads done; c=0,kb=0: phase-1 stores drained
#pragma unroll
            for (int p = 0; p < 2; ++p)
                gl2lds16(yn + (size_t)(m0 + p * 32 + tr) * 256 + kg + csw, As + p * 2048 + t * 8);
#pragma unroll
            for (int p = 0; p < 8; ++p)
                gl2lds16(W1b + (size_t)(c * 256 + p * 32 + tr) * 256 + kg + csw, Bs + p * 2048 + t * 8);
            __syncthreads();   // stage complete & visible
#pragma unroll
            for (int kk = 0; kk < 2; ++kk) {
                const int ac = ((((kk << 2) | quad) ^ (l16 & 7)) << 3);
                bf16x8 af[4], bfv[4];
#pragma unroll
                for (int i = 0; i < 4; i++) af[i]  = *(const bf16x8*)&As[(i * 16 + l16) * 64 + ac];
#pragma unroll
                for (int j = 0; j < 4; j++) bfv[j] = *(const bf16x8*)&Bs[(wc * 64 + j * 16 + l16) * 64 + ac];
#pragma unroll
                for (int i = 0; i < 4; i++)
#pragma unroll
                    for (int j = 0; j < 4; j++)
                        acc1[i][j] = __builtin_amdgcn_mfma_f32_16x16x32_bf16(af[i], bfv[j], acc1[i][j], 0, 0, 0);
            }
        }

        // ---- bias1 + relu -> Hc (bf16, padded stride 264, natural cols)
#pragma unroll
        for (int j = 0; j < 4; j++) {
            const float bb = bias1[c * 256 + c4[j]];
#pragma unroll
            for (int i = 0; i < 4; i++) {
                const int rbase = i * 16 + quad * 4;
#pragma unroll
                for (int r = 0; r < 4; r++) {
                    float v = acc1[i][j][r] + bb;
                    v = v > 0.0f ? v : 0.0f;
                    Hc[(rbase + r) * HSTR + c4[j]] = f2b(v);
                }
            }
        }

        // ---- GEMM2: acc2 += Hc[64x256] @ W2 cols [c*256, c*256+256)
#pragma unroll 1
        for (int kb = 0; kb < 4; ++kb) {
            __syncthreads();   // kb=0: publishes Hc + drains G1 Bs reads; kb>0: drains Bs reads
#pragma unroll
            for (int p = 0; p < 8; ++p)
                gl2lds16(W2b + (size_t)(p * 32 + tr) * 2048 + c * 256 + kb * 64 + csw, Bs + p * 2048 + t * 8);
            __syncthreads();   // stage complete & visible
#pragma unroll
            for (int kk = 0; kk < 2; ++kk) {
                const int ank = kb * 64 + (((kk << 2) | quad) << 3);          // natural (Hc, padded)
                const int ac  = ((((kk << 2) | quad) ^ (l16 & 7)) << 3);      // swizzled (Bs)
                bf16x8 af[4], bfv[4];
#pragma unroll
                for (int i = 0; i < 4; i++) af[i]  = *(const bf16x8*)&Hc[(i * 16 + l16) * HSTR + ank];
#pragma unroll
                for (int j = 0; j < 4; j++) bfv[j] = *(const bf16x8*)&Bs[(wc * 64 + j * 16 + l16) * 64 + ac];
#pragma unroll
                for (int i = 0; i < 4; i++)
#pragma unroll
                    for (int j = 0; j < 4; j++)
                        acc2[i][j] = __builtin_amdgcn_mfma_f32_16x16x32_bf16(af[i], bfv[j], acc2[i][j], 0, 0, 0);
            }
        }
    }

    // ---- epilogue: + bias2 + xb residual -> out (f32)
#pragma unroll
    for (int j = 0; j < 4; j++) {
        const float b2 = bias2[c4[j]];
#pragma unroll
        for (int i = 0; i < 4; i++) {
            const int rbase = m0 + i * 16 + quad * 4;
#pragma unroll
            for (int r = 0; r < 4; r++) {
                const size_t o = (size_t)(rbase + r) * 256 + c4[j];
                out[o] = acc2[i][j][r] + b2 + b2f(xb[o]);
            }
        }
    }
}

extern "C" void kernel_launch(void* const* d_in, const int* in_sizes, int n_in,
                              void* d_out, int out_size, void* d_ws, size_t ws_size,
                              hipStream_t stream) {
    const float* ent   = (const float*)d_in[0];
    const float* w_in  = (const float*)d_in[1];
    const float* w_out = (const float*)d_in[2];
    const float* W1    = (const float*)d_in[3];
    const float* bias1 = (const float*)d_in[4];
    const float* W2    = (const float*)d_in[5];
    const float* bias2 = (const float*)d_in[6];
    const float* g1    = (const float*)d_in[7];
    const float* be1   = (const float*)d_in[8];
    const float* g2    = (const float*)d_in[9];
    const float* be2   = (const float*)d_in[10];
    float* out = (float*)d_out;

    char* ws = (char*)d_ws;
    ushort_t* xn     = (ushort_t*)ws;
    ushort_t* yn     = (ushort_t*)(ws + 16777216);
    ushort_t* xb     = (ushort_t*)(ws + 2 * 16777216);
    ushort_t* bt_in  = (ushort_t*)(ws + 3 * 16777216);
    ushort_t* bt_out = bt_in + WELEM;
    ushort_t* W1b    = bt_out + WELEM;
    ushort_t* W2b    = W1b + WELEM;

    // 1) merged prep: weights->bf16 repack (768 blocks) + LN1 (8192 blocks)
    prep<<<dim3(8960), dim3(256), 0, stream>>>(w_in, w_out, W1, W2,
                                               bt_in, bt_out, W1b, W2b,
                                               ent, g1, be1, xn);
    // 2) fused TT+LN2+FF1+FF2 (grid 512, 2 blocks/CU; per-stripe independent)
    tt_ff<<<dim3(M_SZ / 64), dim3(256), 0, stream>>>(xn, bt_in, bt_out, g2, be2, ent,
                                                     W1b, W2b, bias1, bias2,
                                                     yn, xb, out);
}